// Round 15
// baseline (118.150 us; speedup 1.0000x reference)
//
#include <hip/hip_runtime.h>
#include <math.h>

#define FINF 3.0e38f

typedef __attribute__((ext_vector_type(8))) short short8v;   // 8 bf16 (4 VGPRs)
typedef __attribute__((ext_vector_type(4))) float float4v;   // MFMA acc

__device__ __forceinline__ unsigned short f2bf(float f) {
  unsigned u = __float_as_uint(f);
  unsigned r = u + 0x7FFFu + ((u >> 16) & 1u);  // RNE
  return (unsigned short)(r >> 16);
}

// ---------------- prep: W1 -> bf16 wt2[tap][oc][ic]; zero hist/cnt ----------------
__global__ void k_prep(const float* __restrict__ w1, unsigned short* __restrict__ wt2,
                       unsigned* __restrict__ hist, int* __restrict__ cnt) {
  const int idx = blockIdx.x * 256 + threadIdx.x;  // 294912 = 9*128*256
  if (idx < 294912) {
    const int ic = idx & 255;
    const int r = idx >> 8;
    const int oc = r & 127;
    const int tap = r >> 7;
    wt2[idx] = f2bf(w1[((size_t)oc * 256 + ic) * 9 + tap]);
  }
  if (idx < 16 * 4096) hist[idx] = 0u;
  if (idx < 16) cnt[idx] = 0;
}

// ---------------- conv1 via MFMA (round-7 form, verified) ----------------
__global__ __launch_bounds__(512) void k_conv1m(const float* __restrict__ lat,
                                                const unsigned short* __restrict__ wt2,
                                                float* __restrict__ h1part) {
  const int b = blockIdx.x, ks = blockIdx.y, nh = blockIdx.z;
  const int t = threadIdx.x;
  __shared__ unsigned short sA[1025 * 40];  // 82 KB
  {
    const float4* src = (const float4*)lat + ((size_t)b * 256 + ks * 32) * 256;
#pragma unroll
    for (int i = t; i < 8192; i += 512) {
      const int ic = i >> 8;
      const int q = i & 255;
      const float4 v = src[ic * 256 + q];
      const int px0 = q * 4;
      sA[(px0 + 0) * 40 + ic] = f2bf(v.x);
      sA[(px0 + 1) * 40 + ic] = f2bf(v.y);
      sA[(px0 + 2) * 40 + ic] = f2bf(v.z);
      sA[(px0 + 3) * 40 + ic] = f2bf(v.w);
    }
    if (t < 40) sA[1024 * 40 + t] = 0;
  }
  __syncthreads();

  const int lane = t & 63, wid = t >> 6;
  const int ocbase = nh * 64 + (wid & 1) * 32;
  const int pxbase = (wid >> 1) * 64;
  const int l15 = lane & 15, lg = lane >> 4;

  float4v acc[2][4];
#pragma unroll
  for (int f = 0; f < 2; ++f)
#pragma unroll
    for (int g = 0; g < 4; ++g) acc[f][g] = (float4v){0.f, 0.f, 0.f, 0.f};

#pragma unroll
  for (int tap = 0; tap < 9; ++tap) {
    const int ky = tap / 3, kx = tap % 3;
    short8v aW[2];
#pragma unroll
    for (int f = 0; f < 2; ++f) {
      const int oc = ocbase + f * 16 + l15;
      aW[f] = *(const short8v*)(wt2 + (size_t)(tap * 128 + oc) * 256 + ks * 32 + lg * 8);
    }
    short8v bL[4];
#pragma unroll
    for (int g = 0; g < 4; ++g) {
      const int px = pxbase + g * 16 + l15;
      const int iy = 2 * (px >> 4) - 1 + ky;
      const int ix = 2 * (px & 15) - 1 + kx;
      const int p = (iy >= 0 && ix >= 0) ? iy * 32 + ix : 1024;
      bL[g] = *(const short8v*)(sA + p * 40 + lg * 8);
    }
#pragma unroll
    for (int f = 0; f < 2; ++f)
#pragma unroll
      for (int g = 0; g < 4; ++g)
        acc[f][g] = __builtin_amdgcn_mfma_f32_16x16x32_bf16(aW[f], bL[g], acc[f][g], 0, 0, 0);
  }

  float* dst = h1part + (size_t)ks * 524288 + (size_t)b * 32768;
#pragma unroll
  for (int f = 0; f < 2; ++f)
#pragma unroll
    for (int g = 0; g < 4; ++g)
#pragma unroll
      for (int r = 0; r < 4; ++r) {
        const int oc = ocbase + f * 16 + lg * 4 + r;
        const int px = pxbase + g * 16 + l15;
        dst[oc * 256 + px] = acc[f][g][r];
      }
}

// ---------------- combine 8 ksplit partials + bias + leaky ----------------
__global__ void k_combine(const float* __restrict__ h1p, float* __restrict__ h1,
                          const float* __restrict__ b1) {
  const int i = blockIdx.x * 256 + threadIdx.x;  // float4 index, 131072 total
  const float4* p = (const float4*)h1p;
  float4 a = p[i];
#pragma unroll
  for (int ks = 1; ks < 8; ++ks) {
    const float4 q = p[(size_t)ks * 131072 + i];
    a.x += q.x; a.y += q.y; a.z += q.z; a.w += q.w;
  }
  const int oc = (i >> 6) & 127;
  const float bias = b1[oc];
  float s;
  s = a.x + bias; a.x = s >= 0.f ? s : 0.02f * s;
  s = a.y + bias; a.y = s >= 0.f ? s : 0.02f * s;
  s = a.z + bias; a.z = s >= 0.f ? s : 0.02f * s;
  s = a.w + bias; a.w = s >= 0.f ? s : 0.02f * s;
  ((float4*)h1)[i] = a;
}

// ---------------- histogram of dark channel (also writes dc); XCD-pinned per image ----------------
__global__ __launch_bounds__(256) void k_hist(const float* __restrict__ x,
                                              unsigned* __restrict__ ghist,
                                              float* __restrict__ dc) {
  const int lid = blockIdx.x;
  const int b = (lid & 7) | (((lid >> 3) & 1) << 3);
  const int blk = lid >> 4;
  const int t = threadIdx.x;
  __shared__ unsigned lh[4096];
  for (int i = t; i < 4096; i += 256) lh[i] = 0u;
  __syncthreads();
  const float* xr = x + (size_t)b * 3 * 262144;
  const float* xg = xr + 262144;
  const float* xb = xg + 262144;
  float4* dcb = (float4*)(dc + (size_t)b * 262144);
  const int f0 = blk * 2048;
#pragma unroll
  for (int i = 0; i < 8; ++i) {
    const int f4 = f0 + t + i * 256;
    const float4 r = ((const float4*)xr)[f4];
    const float4 g = ((const float4*)xg)[f4];
    const float4 bl = ((const float4*)xb)[f4];
    float4 d4;
    d4.x = fminf(fminf(r.x, g.x), bl.x); atomicAdd(&lh[min(4095, (int)(d4.x * 4096.f))], 1u);
    d4.y = fminf(fminf(r.y, g.y), bl.y); atomicAdd(&lh[min(4095, (int)(d4.y * 4096.f))], 1u);
    d4.z = fminf(fminf(r.z, g.z), bl.z); atomicAdd(&lh[min(4095, (int)(d4.z * 4096.f))], 1u);
    d4.w = fminf(fminf(r.w, g.w), bl.w); atomicAdd(&lh[min(4095, (int)(d4.w * 4096.f))], 1u);
    dcb[f4] = d4;
  }
  __syncthreads();
  for (int i = t; i < 4096; i += 256)
    if (lh[i]) atomicAdd(&ghist[b * 4096 + i], lh[i]);
}

// ---------------- fused conv2-partial (blocks 0-255) + collect (blocks 256-767) ----------------
__global__ __launch_bounds__(256) void k_c2col(const float* __restrict__ h1,
                                               const float* __restrict__ w2,
                                               float* __restrict__ psum,
                                               const float* __restrict__ x,
                                               const float* __restrict__ dc,
                                               const unsigned* __restrict__ ghist,
                                               int* __restrict__ cnt,
                                               float* __restrict__ candv,
                                               int* __restrict__ candi,
                                               float* __restrict__ bsums) {
  __shared__ union {
    struct { float sW[72]; float red[256]; } a;                                   // conv2 partial
    struct { unsigned h[4096]; unsigned csum[256]; float red[256]; int sB; } c;   // collect
  } sm;
  const int t = threadIdx.x;

  if (blockIdx.x < 256) {
    // ---- conv2 partial: image b, ic-group icg (8 ics)
    const int b = blockIdx.x & 15, icg = blockIdx.x >> 4;
    const int icbase = icg * 8;
    for (int i = t; i < 72; i += 256) sm.a.sW[i] = w2[icbase * 9 + i];
    __syncthreads();
    const int px = t & 63, sub = t >> 6;  // 64 px x 4 subgroups (2 ics each)
    const int oy = px >> 3, ox = px & 7;
    float s = 0.f;
#pragma unroll
    for (int ii = 0; ii < 2; ++ii) {
      const int icl = sub * 2 + ii;
      const float* hp = h1 + ((size_t)b * 128 + icbase + icl) * 256;
      const float* wp = sm.a.sW + icl * 9;
#pragma unroll
      for (int ky = 0; ky < 3; ++ky) {
        const int iy = 2 * oy - 1 + ky;
        if (iy < 0) continue;
#pragma unroll
        for (int kx = 0; kx < 3; ++kx) {
          const int ix = 2 * ox - 1 + kx;
          if (ix < 0) continue;
          s += wp[ky * 3 + kx] * hp[iy * 16 + ix];
        }
      }
    }
    sm.a.red[t] = s;
    __syncthreads();
    for (int off = 128; off > 0; off >>= 1) {
      if (t < off) sm.a.red[t] += sm.a.red[t + off];
      __syncthreads();
    }
    if (t == 0) psum[b * 16 + icg] = sm.a.red[0];
    return;
  }

  // ---- collect (with inline threshold scan)
  const int lid = blockIdx.x - 256;
  const int b = (lid & 7) | (((lid >> 3) & 1) << 3);
  const int blk = lid >> 4;
  for (int i = t; i < 4096; i += 256) sm.c.h[i] = ghist[b * 4096 + i];
  __syncthreads();
  const int top = 4095 - 16 * t;
  unsigned s = 0;
#pragma unroll
  for (int k = 0; k < 16; ++k) s += sm.c.h[top - k];
  sm.c.csum[t] = s;
  __syncthreads();
  for (int off = 1; off < 256; off <<= 1) {
    const unsigned add = (t >= off) ? sm.c.csum[t - off] : 0u;
    __syncthreads();
    sm.c.csum[t] += add;
    __syncthreads();
  }
  {
    const unsigned incl = sm.c.csum[t];
    const unsigned before = incl - s;
    if (before < 262u && incl >= 262u) {
      unsigned cum = before;
      for (int k = 0; k < 16; ++k) {
        const unsigned c = sm.c.h[top - k];
        if (cum + c >= 262u) { sm.c.sB = top - k; break; }
        cum += c;
      }
    }
  }
  __syncthreads();
  const int B = sm.c.sB;
  const float* xr = x + (size_t)b * 3 * 262144;
  const float* xg = xr + 262144;
  const float* xb = xg + 262144;
  const float4* dcb = (const float4*)(dc + (size_t)b * 262144);
  const int f0 = blk * 2048;
  float s0 = 0.f, s1 = 0.f, s2 = 0.f;
#pragma unroll
  for (int i = 0; i < 8; ++i) {
    const int f4 = f0 + t + i * 256;
    const float4 d4 = dcb[f4];
    const float dv[4] = {d4.x, d4.y, d4.z, d4.w};
#pragma unroll
    for (int j = 0; j < 4; ++j) {
      const int bin = min(4095, (int)(dv[j] * 4096.f));
      if (bin >= B) {
        const int idx = f4 * 4 + j;
        if (bin > B) {
          s0 += xr[idx]; s1 += xg[idx]; s2 += xb[idx];
        } else {
          const int k = atomicAdd(&cnt[b], 1);
          if (k < 4096) { candv[b * 4096 + k] = dv[j]; candi[b * 4096 + k] = idx; }
        }
      }
    }
  }
  sm.c.red[t] = s0; __syncthreads();
  for (int off = 128; off > 0; off >>= 1) { if (t < off) sm.c.red[t] += sm.c.red[t + off]; __syncthreads(); }
  if (t == 0) bsums[((size_t)b * 32 + blk) * 3 + 0] = sm.c.red[0];
  __syncthreads();
  sm.c.red[t] = s1; __syncthreads();
  for (int off = 128; off > 0; off >>= 1) { if (t < off) sm.c.red[t] += sm.c.red[t + off]; __syncthreads(); }
  if (t == 0) bsums[((size_t)b * 32 + blk) * 3 + 1] = sm.c.red[0];
  __syncthreads();
  sm.c.red[t] = s2; __syncthreads();
  for (int off = 128; off > 0; off >>= 1) { if (t < off) sm.c.red[t] += sm.c.red[t + off]; __syncthreads(); }
  if (t == 0) bsums[((size_t)b * 32 + blk) * 3 + 2] = sm.c.red[0];
}

// ---------------- finalize A + params: psum reduce + rneed scan + wave-parallel argmax ----------------
__global__ void k_finalA(const float* __restrict__ x, const float* __restrict__ bsums,
                         const int* __restrict__ cnt, const unsigned* __restrict__ ghist,
                         const float* __restrict__ candv, const int* __restrict__ candi,
                         const float* __restrict__ psum, const float* __restrict__ b2,
                         const float* __restrict__ w3, const float* __restrict__ b3,
                         float* __restrict__ params, float* __restrict__ Av) {
  const int b = blockIdx.x;
  const int t = threadIdx.x;  // 64 = one wave
  __shared__ float sv[4096];
  __shared__ int si[4096];
  __shared__ int sR;
  // params[b]: reduce 16 conv2 partials + bias + 1x1 conv + tanh
  {
    float p = (t < 16) ? psum[b * 16 + t] : 0.f;
#pragma unroll
    for (int off = 8; off > 0; off >>= 1) p += __shfl_xor(p, off);
    if (t == 0) {
      const float mean = p / 64.f + b2[0];
      const float h = w3[0] * mean + b3[0];
      params[b] = tanhf(h) * 0.5f + 0.5f;
    }
  }
  // inline scan for rneed: thread t covers bins [4095-64t .. 4095-64t-63]
  {
    const int base = 4095 - 64 * t;
    unsigned ssum = 0;
    for (int k = 0; k < 64; ++k) ssum += ghist[b * 4096 + base - k];
    unsigned incl = ssum;
    for (int off = 1; off < 64; off <<= 1) {
      const unsigned v = __shfl_up(incl, off);
      if (t >= off) incl += v;
    }
    const unsigned before = incl - ssum;
    if (before < 262u && incl >= 262u) {
      unsigned cum = before;
      for (int k = 0; k < 64; ++k) {
        const unsigned c = ghist[b * 4096 + base - k];
        if (cum + c >= 262u) { sR = (int)(262u - cum); break; }
        cum += c;
      }
    }
  }
  // parallel bsums reduction (32 partials x 3)
  float S0 = 0.f, S1 = 0.f, S2 = 0.f;
  if (t < 32) {
    S0 = bsums[((size_t)b * 32 + t) * 3 + 0];
    S1 = bsums[((size_t)b * 32 + t) * 3 + 1];
    S2 = bsums[((size_t)b * 32 + t) * 3 + 2];
  }
#pragma unroll
  for (int off = 32; off > 0; off >>= 1) {
    S0 += __shfl_xor(S0, off);
    S1 += __shfl_xor(S1, off);
    S2 += __shfl_xor(S2, off);
  }
  const int n = min(cnt[b], 4096);
  for (int i = t; i < n; i += 64) { sv[i] = candv[b * 4096 + i]; si[i] = candi[b * 4096 + i]; }
  __syncthreads();
  const int r = sR;
  const float* xr = x + (size_t)b * 3 * 262144;
  const float* xg = xr + 262144;
  const float* xb = xg + 262144;
  for (int sel = 0; sel < r; ++sel) {
    float bv = -1.f; int bi = 0x7FFFFFFF; int bx = -1;
    for (int i = t; i < n; i += 64) {
      const float v = sv[i];
      const int id = si[i];
      if (v > bv || (v == bv && id < bi)) { bv = v; bi = id; bx = i; }
    }
#pragma unroll
    for (int off = 32; off > 0; off >>= 1) {
      const float ov = __shfl_xor(bv, off);
      const int oid = __shfl_xor(bi, off);
      const int obx = __shfl_xor(bx, off);
      if (ov > bv || (ov == bv && oid < bi)) { bv = ov; bi = oid; bx = obx; }
    }
    if (bx < 0) break;  // uniform across lanes
    if (t == 0) {
      sv[bx] = -1.f;
      S0 += xr[bi]; S1 += xg[bi]; S2 += xb[bi];
    }
    __syncthreads();
  }
  if (t == 0) {
    Av[b * 3 + 0] = S0 / 262.f;
    Av[b * 3 + 1] = S1 / 262.f;
    Av[b * 3 + 2] = S2 / 262.f;
  }
}

// ---------------- dc2 + 7x7 min-pool + dehaze -> unnormalized out + minmax; 2 barriers ----------------
// Stage all 14 dc rows once; each thread owns 2 columns for ALL rows, so hmin (horizontal)
// comes from LDS and the vertical min + T + o-values stay in registers. Writes unnormalized out.
__global__ __launch_bounds__(256) void k_dchv(const float* __restrict__ x,
                                              const float* __restrict__ Av,
                                              const float* __restrict__ params,
                                              float* __restrict__ out,
                                              float2* __restrict__ pmm) {
  const int lid = blockIdx.x;                    // 1024
  const int swz = (lid & 7) * 128 + (lid >> 3);  // XCD-chunked: image b -> XCD (b>>1)
  const int b = swz >> 6;
  const int y0 = (swz & 63) * 8;
  const int t = threadIdx.x;
  __shared__ float ds[14][520];  // 29.1 KB
  const float a0 = Av[b * 3 + 0], a1 = Av[b * 3 + 1], a2 = Av[b * 3 + 2];
  const float pb = params[b];
  const float* xb = x + (size_t)b * 3 * 262144;
  float* ob = out + (size_t)b * 3 * 262144;
  // stage 14 dc rows (pad cols + invalid rows = FINF)
#pragma unroll 2
  for (int i = 0; i < 14; ++i) {
    const int row = y0 - 3 + i;
    if (row >= 0 && row < 512) {
      const float2 r  = ((const float2*)(xb + (size_t)row * 512))[t];
      const float2 g  = ((const float2*)(xb + 262144 + (size_t)row * 512))[t];
      const float2 bl = ((const float2*)(xb + 524288 + (size_t)row * 512))[t];
      ds[i][3 + 2 * t]     = fminf(fminf(r.x / a0, g.x / a1), bl.x / a2);
      ds[i][3 + 2 * t + 1] = fminf(fminf(r.y / a0, g.y / a1), bl.y / a2);
    } else {
      ds[i][3 + 2 * t]     = FINF;
      ds[i][3 + 2 * t + 1] = FINF;
    }
    if (t < 3) { ds[i][t] = FINF; ds[i][515 + t] = FINF; }
  }
  __syncthreads();
  // per-thread horizontal mins for its 2 columns, all 14 rows (registers)
  float hm0[14], hm1[14];
#pragma unroll
  for (int i = 0; i < 14; ++i) {
    float m0 = ds[i][2 * t], m1 = ds[i][2 * t + 1];
#pragma unroll
    for (int k = 1; k < 7; ++k) {
      m0 = fminf(m0, ds[i][2 * t + k]);
      m1 = fminf(m1, ds[i][2 * t + 1 + k]);
    }
    hm0[i] = m0; hm1[i] = m1;
  }
  // vertical min + dehaze + unnormalized out + minmax
  float lmin = FINF, lmax = -FINF;
#pragma unroll
  for (int j = 0; j < 8; ++j) {
    const int y = y0 + j;
    float v0 = hm0[j], v1 = hm1[j];
#pragma unroll
    for (int k = 1; k < 7; ++k) {
      v0 = fminf(v0, hm0[j + k]);
      v1 = fminf(v1, hm1[j + k]);
    }
    const float i0 = 1.f / fmaxf(1.f - pb * v0, 0.01f);
    const float i1 = 1.f / fmaxf(1.f - pb * v1, 0.01f);
#pragma unroll
    for (int c = 0; c < 3; ++c) {
      const float a = (c == 0) ? a0 : ((c == 1) ? a1 : a2);
      const float2 xv = ((const float2*)(xb + (size_t)c * 262144 + (size_t)y * 512))[t];
      const float o0 = fmaf(xv.x - a, i0, a);
      const float o1 = fmaf(xv.y - a, i1, a);
      lmin = fminf(lmin, fminf(o0, o1));
      lmax = fmaxf(lmax, fmaxf(o0, o1));
      ((float2*)(ob + (size_t)c * 262144 + (size_t)y * 512))[t] = make_float2(o0, o1);
    }
  }
  __shared__ float red[256];
  red[t] = lmin; __syncthreads();
  for (int off = 128; off > 0; off >>= 1) { if (t < off) red[t] = fminf(red[t], red[t + off]); __syncthreads(); }
  const float bmin = red[0];
  __syncthreads();
  red[t] = lmax; __syncthreads();
  for (int off = 128; off > 0; off >>= 1) { if (t < off) red[t] = fmaxf(red[t], red[t + off]); __syncthreads(); }
  if (t == 0) pmm[lid] = make_float2(bmin, red[0]);
}

// ---------------- final pass: pmm reduce (deterministic per block) + in-place normalize of out ----------------
__global__ __launch_bounds__(256) void k_norm2(float* __restrict__ out,
                                               const float2* __restrict__ pmm) {
  const int t = threadIdx.x;
  __shared__ float rmn[256], rmx[256];
  float mn, sc;
  {
    float m0 = FINF, m1 = -FINF;
    for (int i = t; i < 1024; i += 256) {
      const float2 v = pmm[i];
      m0 = fminf(m0, v.x);
      m1 = fmaxf(m1, v.y);
    }
    rmn[t] = m0; rmx[t] = m1;
    __syncthreads();
    for (int off = 128; off > 0; off >>= 1) {
      if (t < off) {
        rmn[t] = fminf(rmn[t], rmn[t + off]);
        rmx[t] = fmaxf(rmx[t], rmx[t + off]);
      }
      __syncthreads();
    }
    mn = rmn[0];
    sc = 1.f / (rmx[0] - mn);
  }
  // 12582912 floats = 3145728 float4 over 4096 blocks x 256 thr = 3 float4/thread
  float4* o4 = (float4*)out;
  const int base = blockIdx.x * 768 + t;
#pragma unroll
  for (int i = 0; i < 3; ++i) {
    float4 v = o4[base + i * 256];
    v.x = (v.x - mn) * sc;
    v.y = (v.y - mn) * sc;
    v.z = (v.z - mn) * sc;
    v.w = (v.w - mn) * sc;
    o4[base + i * 256] = v;
  }
}

extern "C" void kernel_launch(void* const* d_in, const int* in_sizes, int n_in,
                              void* d_out, int out_size, void* d_ws, size_t ws_size,
                              hipStream_t stream) {
  const float* x   = (const float*)d_in[0];
  const float* lat = (const float*)d_in[1];
  const float* w1  = (const float*)d_in[2];
  const float* b1  = (const float*)d_in[3];
  const float* w2  = (const float*)d_in[4];
  const float* b2  = (const float*)d_in[5];
  const float* w3  = (const float*)d_in[6];
  const float* b3  = (const float*)d_in[7];
  float* out = (float*)d_out;

  char* ws = (char*)d_ws;
  size_t off = 0;
  auto alloc = [&](size_t sz) -> void* {
    off = (off + 255) & ~(size_t)255;
    void* p = ws + off;
    off += sz;
    return p;
  };
  // One 16 MB region time-shared: h1part (conv) -> dc (hist/collect). vm eliminated.
  float*    big   = (float*)alloc((size_t)16 * 512 * 512 * sizeof(float));
  float*    h1p   = big;
  float*    dc    = big;
  float*    h1    = (float*)alloc(524288 * sizeof(float));
  unsigned short* wt2 = (unsigned short*)alloc(294912 * sizeof(unsigned short));
  float*    paramsp = (float*)alloc(16 * sizeof(float));
  float*    psum  = (float*)alloc(16 * 16 * sizeof(float));
  unsigned* hist  = (unsigned*)alloc(16 * 4096 * sizeof(unsigned));
  int*      cnt   = (int*)alloc(16 * sizeof(int));
  float*    bsums = (float*)alloc(16 * 32 * 3 * sizeof(float));
  float*    candv = (float*)alloc(16 * 4096 * sizeof(float));
  int*      candi = (int*)alloc(16 * 4096 * sizeof(int));
  float*    Av    = (float*)alloc(16 * 3 * sizeof(float));
  float2*   pmm   = (float2*)alloc(1024 * sizeof(float2));

  k_prep<<<1152, 256, 0, stream>>>(w1, wt2, hist, cnt);
  k_conv1m<<<dim3(16, 8, 2), 512, 0, stream>>>(lat, wt2, h1p);
  k_combine<<<512, 256, 0, stream>>>(h1p, h1, b1);   // must precede k_hist (big aliasing)
  k_hist<<<512, 256, 0, stream>>>(x, hist, dc);
  k_c2col<<<768, 256, 0, stream>>>(h1, w2, psum,
                                   x, dc, hist, cnt, candv, candi, bsums);
  k_finalA<<<16, 64, 0, stream>>>(x, bsums, cnt, hist, candv, candi,
                                  psum, b2, w3, b3, paramsp, Av);
  k_dchv<<<1024, 256, 0, stream>>>(x, Av, paramsp, out, pmm);
  k_norm2<<<4096, 256, 0, stream>>>(out, pmm);
}

// Round 16
// 113.342 us; speedup vs baseline: 1.0424x; 1.0424x over previous
//
#include <hip/hip_runtime.h>
#include <math.h>

#define FINF 3.0e38f

typedef __attribute__((ext_vector_type(8))) short short8v;   // 8 bf16 (4 VGPRs)
typedef __attribute__((ext_vector_type(4))) float float4v;   // MFMA acc

__device__ __forceinline__ unsigned short f2bf(float f) {
  unsigned u = __float_as_uint(f);
  unsigned r = u + 0x7FFFu + ((u >> 16) & 1u);  // RNE
  return (unsigned short)(r >> 16);
}

// ---------------- prep: W1 -> bf16 wt2[tap][oc][ic]; zero hist/cnt ----------------
__global__ void k_prep(const float* __restrict__ w1, unsigned short* __restrict__ wt2,
                       unsigned* __restrict__ hist, int* __restrict__ cnt) {
  const int idx = blockIdx.x * 256 + threadIdx.x;  // 294912 = 9*128*256
  if (idx < 294912) {
    const int ic = idx & 255;
    const int r = idx >> 8;
    const int oc = r & 127;
    const int tap = r >> 7;
    wt2[idx] = f2bf(w1[((size_t)oc * 256 + ic) * 9 + tap]);
  }
  if (idx < 16 * 4096) hist[idx] = 0u;
  if (idx < 16) cnt[idx] = 0;
}

// ---------------- conv1 via MFMA (round-7 form, verified) ----------------
__global__ __launch_bounds__(512) void k_conv1m(const float* __restrict__ lat,
                                                const unsigned short* __restrict__ wt2,
                                                float* __restrict__ h1part) {
  const int b = blockIdx.x, ks = blockIdx.y, nh = blockIdx.z;
  const int t = threadIdx.x;
  __shared__ unsigned short sA[1025 * 40];  // 82 KB
  {
    const float4* src = (const float4*)lat + ((size_t)b * 256 + ks * 32) * 256;
#pragma unroll
    for (int i = t; i < 8192; i += 512) {
      const int ic = i >> 8;
      const int q = i & 255;
      const float4 v = src[ic * 256 + q];
      const int px0 = q * 4;
      sA[(px0 + 0) * 40 + ic] = f2bf(v.x);
      sA[(px0 + 1) * 40 + ic] = f2bf(v.y);
      sA[(px0 + 2) * 40 + ic] = f2bf(v.z);
      sA[(px0 + 3) * 40 + ic] = f2bf(v.w);
    }
    if (t < 40) sA[1024 * 40 + t] = 0;
  }
  __syncthreads();

  const int lane = t & 63, wid = t >> 6;
  const int ocbase = nh * 64 + (wid & 1) * 32;
  const int pxbase = (wid >> 1) * 64;
  const int l15 = lane & 15, lg = lane >> 4;

  float4v acc[2][4];
#pragma unroll
  for (int f = 0; f < 2; ++f)
#pragma unroll
    for (int g = 0; g < 4; ++g) acc[f][g] = (float4v){0.f, 0.f, 0.f, 0.f};

#pragma unroll
  for (int tap = 0; tap < 9; ++tap) {
    const int ky = tap / 3, kx = tap % 3;
    short8v aW[2];
#pragma unroll
    for (int f = 0; f < 2; ++f) {
      const int oc = ocbase + f * 16 + l15;
      aW[f] = *(const short8v*)(wt2 + (size_t)(tap * 128 + oc) * 256 + ks * 32 + lg * 8);
    }
    short8v bL[4];
#pragma unroll
    for (int g = 0; g < 4; ++g) {
      const int px = pxbase + g * 16 + l15;
      const int iy = 2 * (px >> 4) - 1 + ky;
      const int ix = 2 * (px & 15) - 1 + kx;
      const int p = (iy >= 0 && ix >= 0) ? iy * 32 + ix : 1024;
      bL[g] = *(const short8v*)(sA + p * 40 + lg * 8);
    }
#pragma unroll
    for (int f = 0; f < 2; ++f)
#pragma unroll
      for (int g = 0; g < 4; ++g)
        acc[f][g] = __builtin_amdgcn_mfma_f32_16x16x32_bf16(aW[f], bL[g], acc[f][g], 0, 0, 0);
  }

  float* dst = h1part + (size_t)ks * 524288 + (size_t)b * 32768;
#pragma unroll
  for (int f = 0; f < 2; ++f)
#pragma unroll
    for (int g = 0; g < 4; ++g)
#pragma unroll
      for (int r = 0; r < 4; ++r) {
        const int oc = ocbase + f * 16 + lg * 4 + r;
        const int px = pxbase + g * 16 + l15;
        dst[oc * 256 + px] = acc[f][g][r];
      }
}

// ---------------- combine 8 ksplit partials + bias + leaky ----------------
__global__ void k_combine(const float* __restrict__ h1p, float* __restrict__ h1,
                          const float* __restrict__ b1) {
  const int i = blockIdx.x * 256 + threadIdx.x;  // float4 index, 131072 total
  const float4* p = (const float4*)h1p;
  float4 a = p[i];
#pragma unroll
  for (int ks = 1; ks < 8; ++ks) {
    const float4 q = p[(size_t)ks * 131072 + i];
    a.x += q.x; a.y += q.y; a.z += q.z; a.w += q.w;
  }
  const int oc = (i >> 6) & 127;
  const float bias = b1[oc];
  float s;
  s = a.x + bias; a.x = s >= 0.f ? s : 0.02f * s;
  s = a.y + bias; a.y = s >= 0.f ? s : 0.02f * s;
  s = a.z + bias; a.z = s >= 0.f ? s : 0.02f * s;
  s = a.w + bias; a.w = s >= 0.f ? s : 0.02f * s;
  ((float4*)h1)[i] = a;
}

// ---------------- histogram of dark channel (also writes dc); XCD-pinned per image ----------------
__global__ __launch_bounds__(256) void k_hist(const float* __restrict__ x,
                                              unsigned* __restrict__ ghist,
                                              float* __restrict__ dc) {
  const int lid = blockIdx.x;
  const int b = (lid & 7) | (((lid >> 3) & 1) << 3);
  const int blk = lid >> 4;
  const int t = threadIdx.x;
  __shared__ unsigned lh[4096];
  for (int i = t; i < 4096; i += 256) lh[i] = 0u;
  __syncthreads();
  const float* xr = x + (size_t)b * 3 * 262144;
  const float* xg = xr + 262144;
  const float* xb = xg + 262144;
  float4* dcb = (float4*)(dc + (size_t)b * 262144);
  const int f0 = blk * 2048;
#pragma unroll
  for (int i = 0; i < 8; ++i) {
    const int f4 = f0 + t + i * 256;
    const float4 r = ((const float4*)xr)[f4];
    const float4 g = ((const float4*)xg)[f4];
    const float4 bl = ((const float4*)xb)[f4];
    float4 d4;
    d4.x = fminf(fminf(r.x, g.x), bl.x); atomicAdd(&lh[min(4095, (int)(d4.x * 4096.f))], 1u);
    d4.y = fminf(fminf(r.y, g.y), bl.y); atomicAdd(&lh[min(4095, (int)(d4.y * 4096.f))], 1u);
    d4.z = fminf(fminf(r.z, g.z), bl.z); atomicAdd(&lh[min(4095, (int)(d4.z * 4096.f))], 1u);
    d4.w = fminf(fminf(r.w, g.w), bl.w); atomicAdd(&lh[min(4095, (int)(d4.w * 4096.f))], 1u);
    dcb[f4] = d4;
  }
  __syncthreads();
  for (int i = t; i < 4096; i += 256)
    if (lh[i]) atomicAdd(&ghist[b * 4096 + i], lh[i]);
}

// ---------------- fused conv2-partial (blocks 0-255) + collect (blocks 256-767) ----------------
__global__ __launch_bounds__(256) void k_c2col(const float* __restrict__ h1,
                                               const float* __restrict__ w2,
                                               float* __restrict__ psum,
                                               const float* __restrict__ x,
                                               const float* __restrict__ dc,
                                               const unsigned* __restrict__ ghist,
                                               int* __restrict__ cnt,
                                               float* __restrict__ candv,
                                               int* __restrict__ candi,
                                               float* __restrict__ bsums) {
  __shared__ union {
    struct { float sW[72]; float red[256]; } a;                                   // conv2 partial
    struct { unsigned h[4096]; unsigned csum[256]; float red[256]; int sB; } c;   // collect
  } sm;
  const int t = threadIdx.x;

  if (blockIdx.x < 256) {
    // ---- conv2 partial: image b, ic-group icg (8 ics)
    const int b = blockIdx.x & 15, icg = blockIdx.x >> 4;
    const int icbase = icg * 8;
    for (int i = t; i < 72; i += 256) sm.a.sW[i] = w2[icbase * 9 + i];
    __syncthreads();
    const int px = t & 63, sub = t >> 6;  // 64 px x 4 subgroups (2 ics each)
    const int oy = px >> 3, ox = px & 7;
    float s = 0.f;
#pragma unroll
    for (int ii = 0; ii < 2; ++ii) {
      const int icl = sub * 2 + ii;
      const float* hp = h1 + ((size_t)b * 128 + icbase + icl) * 256;
      const float* wp = sm.a.sW + icl * 9;
#pragma unroll
      for (int ky = 0; ky < 3; ++ky) {
        const int iy = 2 * oy - 1 + ky;
        if (iy < 0) continue;
#pragma unroll
        for (int kx = 0; kx < 3; ++kx) {
          const int ix = 2 * ox - 1 + kx;
          if (ix < 0) continue;
          s += wp[ky * 3 + kx] * hp[iy * 16 + ix];
        }
      }
    }
    sm.a.red[t] = s;
    __syncthreads();
    for (int off = 128; off > 0; off >>= 1) {
      if (t < off) sm.a.red[t] += sm.a.red[t + off];
      __syncthreads();
    }
    if (t == 0) psum[b * 16 + icg] = sm.a.red[0];
    return;
  }

  // ---- collect (with inline threshold scan)
  const int lid = blockIdx.x - 256;
  const int b = (lid & 7) | (((lid >> 3) & 1) << 3);
  const int blk = lid >> 4;
  for (int i = t; i < 4096; i += 256) sm.c.h[i] = ghist[b * 4096 + i];
  __syncthreads();
  const int top = 4095 - 16 * t;
  unsigned s = 0;
#pragma unroll
  for (int k = 0; k < 16; ++k) s += sm.c.h[top - k];
  sm.c.csum[t] = s;
  __syncthreads();
  for (int off = 1; off < 256; off <<= 1) {
    const unsigned add = (t >= off) ? sm.c.csum[t - off] : 0u;
    __syncthreads();
    sm.c.csum[t] += add;
    __syncthreads();
  }
  {
    const unsigned incl = sm.c.csum[t];
    const unsigned before = incl - s;
    if (before < 262u && incl >= 262u) {
      unsigned cum = before;
      for (int k = 0; k < 16; ++k) {
        const unsigned c = sm.c.h[top - k];
        if (cum + c >= 262u) { sm.c.sB = top - k; break; }
        cum += c;
      }
    }
  }
  __syncthreads();
  const int B = sm.c.sB;
  const float* xr = x + (size_t)b * 3 * 262144;
  const float* xg = xr + 262144;
  const float* xb = xg + 262144;
  const float4* dcb = (const float4*)(dc + (size_t)b * 262144);
  const int f0 = blk * 2048;
  float s0 = 0.f, s1 = 0.f, s2 = 0.f;
#pragma unroll
  for (int i = 0; i < 8; ++i) {
    const int f4 = f0 + t + i * 256;
    const float4 d4 = dcb[f4];
    const float dv[4] = {d4.x, d4.y, d4.z, d4.w};
#pragma unroll
    for (int j = 0; j < 4; ++j) {
      const int bin = min(4095, (int)(dv[j] * 4096.f));
      if (bin >= B) {
        const int idx = f4 * 4 + j;
        if (bin > B) {
          s0 += xr[idx]; s1 += xg[idx]; s2 += xb[idx];
        } else {
          const int k = atomicAdd(&cnt[b], 1);
          if (k < 4096) { candv[b * 4096 + k] = dv[j]; candi[b * 4096 + k] = idx; }
        }
      }
    }
  }
  sm.c.red[t] = s0; __syncthreads();
  for (int off = 128; off > 0; off >>= 1) { if (t < off) sm.c.red[t] += sm.c.red[t + off]; __syncthreads(); }
  if (t == 0) bsums[((size_t)b * 32 + blk) * 3 + 0] = sm.c.red[0];
  __syncthreads();
  sm.c.red[t] = s1; __syncthreads();
  for (int off = 128; off > 0; off >>= 1) { if (t < off) sm.c.red[t] += sm.c.red[t + off]; __syncthreads(); }
  if (t == 0) bsums[((size_t)b * 32 + blk) * 3 + 1] = sm.c.red[0];
  __syncthreads();
  sm.c.red[t] = s2; __syncthreads();
  for (int off = 128; off > 0; off >>= 1) { if (t < off) sm.c.red[t] += sm.c.red[t + off]; __syncthreads(); }
  if (t == 0) bsums[((size_t)b * 32 + blk) * 3 + 2] = sm.c.red[0];
}

// ---------------- finalize A + params: psum reduce + rneed scan + wave-parallel argmax ----------------
__global__ void k_finalA(const float* __restrict__ x, const float* __restrict__ bsums,
                         const int* __restrict__ cnt, const unsigned* __restrict__ ghist,
                         const float* __restrict__ candv, const int* __restrict__ candi,
                         const float* __restrict__ psum, const float* __restrict__ b2,
                         const float* __restrict__ w3, const float* __restrict__ b3,
                         float* __restrict__ params, float* __restrict__ Av) {
  const int b = blockIdx.x;
  const int t = threadIdx.x;  // 64 = one wave
  __shared__ float sv[4096];
  __shared__ int si[4096];
  __shared__ int sR;
  // params[b]: reduce 16 conv2 partials + bias + 1x1 conv + tanh
  {
    float p = (t < 16) ? psum[b * 16 + t] : 0.f;
#pragma unroll
    for (int off = 8; off > 0; off >>= 1) p += __shfl_xor(p, off);
    if (t == 0) {
      const float mean = p / 64.f + b2[0];
      const float h = w3[0] * mean + b3[0];
      params[b] = tanhf(h) * 0.5f + 0.5f;
    }
  }
  // inline scan for rneed: thread t covers bins [4095-64t .. 4095-64t-63]
  {
    const int base = 4095 - 64 * t;
    unsigned ssum = 0;
    for (int k = 0; k < 64; ++k) ssum += ghist[b * 4096 + base - k];
    unsigned incl = ssum;
    for (int off = 1; off < 64; off <<= 1) {
      const unsigned v = __shfl_up(incl, off);
      if (t >= off) incl += v;
    }
    const unsigned before = incl - ssum;
    if (before < 262u && incl >= 262u) {
      unsigned cum = before;
      for (int k = 0; k < 64; ++k) {
        const unsigned c = ghist[b * 4096 + base - k];
        if (cum + c >= 262u) { sR = (int)(262u - cum); break; }
        cum += c;
      }
    }
  }
  // parallel bsums reduction (32 partials x 3)
  float S0 = 0.f, S1 = 0.f, S2 = 0.f;
  if (t < 32) {
    S0 = bsums[((size_t)b * 32 + t) * 3 + 0];
    S1 = bsums[((size_t)b * 32 + t) * 3 + 1];
    S2 = bsums[((size_t)b * 32 + t) * 3 + 2];
  }
#pragma unroll
  for (int off = 32; off > 0; off >>= 1) {
    S0 += __shfl_xor(S0, off);
    S1 += __shfl_xor(S1, off);
    S2 += __shfl_xor(S2, off);
  }
  const int n = min(cnt[b], 4096);
  for (int i = t; i < n; i += 64) { sv[i] = candv[b * 4096 + i]; si[i] = candi[b * 4096 + i]; }
  __syncthreads();
  const int r = sR;
  const float* xr = x + (size_t)b * 3 * 262144;
  const float* xg = xr + 262144;
  const float* xb = xg + 262144;
  for (int sel = 0; sel < r; ++sel) {
    float bv = -1.f; int bi = 0x7FFFFFFF; int bx = -1;
    for (int i = t; i < n; i += 64) {
      const float v = sv[i];
      const int id = si[i];
      if (v > bv || (v == bv && id < bi)) { bv = v; bi = id; bx = i; }
    }
#pragma unroll
    for (int off = 32; off > 0; off >>= 1) {
      const float ov = __shfl_xor(bv, off);
      const int oid = __shfl_xor(bi, off);
      const int obx = __shfl_xor(bx, off);
      if (ov > bv || (ov == bv && oid < bi)) { bv = ov; bi = oid; bx = obx; }
    }
    if (bx < 0) break;  // uniform across lanes
    if (t == 0) {
      sv[bx] = -1.f;
      S0 += xr[bi]; S1 += xg[bi]; S2 += xb[bi];
    }
    __syncthreads();
  }
  if (t == 0) {
    Av[b * 3 + 0] = S0 / 262.f;
    Av[b * 3 + 1] = S1 / 262.f;
    Av[b * 3 + 2] = S2 / 262.f;
  }
}

// ---------------- dc2 + 7x7 min-pool -> vm + minmax partials; 2 barriers (register hmin) ----------------
// Stage all 14 dc rows once; each thread owns 2 columns for ALL rows -> hmin + vertical min +
// T + o-minmax in registers. Writes only the compact vm map (16 MB); out written once by k_norm2.
__global__ __launch_bounds__(256) void k_dchv(const float* __restrict__ x,
                                              const float* __restrict__ Av,
                                              const float* __restrict__ params,
                                              float* __restrict__ vm,
                                              float2* __restrict__ pmm) {
  const int lid = blockIdx.x;                    // 1024
  const int swz = (lid & 7) * 128 + (lid >> 3);  // XCD-chunked: image b -> XCD (b>>1)
  const int b = swz >> 6;
  const int y0 = (swz & 63) * 8;
  const int t = threadIdx.x;
  __shared__ float ds[14][520];  // 29.1 KB
  const float a0 = Av[b * 3 + 0], a1 = Av[b * 3 + 1], a2 = Av[b * 3 + 2];
  const float pb = params[b];
  const float* xb = x + (size_t)b * 3 * 262144;
  float* vmb = vm + (size_t)b * 262144;
  // stage 14 dc rows (pad cols + invalid rows = FINF)
#pragma unroll 2
  for (int i = 0; i < 14; ++i) {
    const int row = y0 - 3 + i;
    if (row >= 0 && row < 512) {
      const float2 r  = ((const float2*)(xb + (size_t)row * 512))[t];
      const float2 g  = ((const float2*)(xb + 262144 + (size_t)row * 512))[t];
      const float2 bl = ((const float2*)(xb + 524288 + (size_t)row * 512))[t];
      ds[i][3 + 2 * t]     = fminf(fminf(r.x / a0, g.x / a1), bl.x / a2);
      ds[i][3 + 2 * t + 1] = fminf(fminf(r.y / a0, g.y / a1), bl.y / a2);
    } else {
      ds[i][3 + 2 * t]     = FINF;
      ds[i][3 + 2 * t + 1] = FINF;
    }
    if (t < 3) { ds[i][t] = FINF; ds[i][515 + t] = FINF; }
  }
  __syncthreads();
  // per-thread horizontal mins for its 2 columns, all 14 rows (registers)
  float hm0[14], hm1[14];
#pragma unroll
  for (int i = 0; i < 14; ++i) {
    float m0 = ds[i][2 * t], m1 = ds[i][2 * t + 1];
#pragma unroll
    for (int k = 1; k < 7; ++k) {
      m0 = fminf(m0, ds[i][2 * t + k]);
      m1 = fminf(m1, ds[i][2 * t + 1 + k]);
    }
    hm0[i] = m0; hm1[i] = m1;
  }
  // vertical min -> vm; track out-minmax via registers (same exprs as k_norm2 recompute)
  float lmin = FINF, lmax = -FINF;
#pragma unroll
  for (int j = 0; j < 8; ++j) {
    const int y = y0 + j;
    float v0 = hm0[j], v1 = hm1[j];
#pragma unroll
    for (int k = 1; k < 7; ++k) {
      v0 = fminf(v0, hm0[j + k]);
      v1 = fminf(v1, hm1[j + k]);
    }
    ((float2*)(vmb + (size_t)y * 512))[t] = make_float2(v0, v1);
    const float i0 = 1.f / fmaxf(1.f - pb * v0, 0.01f);
    const float i1 = 1.f / fmaxf(1.f - pb * v1, 0.01f);
#pragma unroll
    for (int c = 0; c < 3; ++c) {
      const float a = (c == 0) ? a0 : ((c == 1) ? a1 : a2);
      const float2 xv = ((const float2*)(xb + (size_t)c * 262144 + (size_t)y * 512))[t];
      const float o0 = fmaf(xv.x - a, i0, a);
      const float o1 = fmaf(xv.y - a, i1, a);
      lmin = fminf(lmin, fminf(o0, o1));
      lmax = fmaxf(lmax, fmaxf(o0, o1));
    }
  }
  __shared__ float red[256];
  red[t] = lmin; __syncthreads();
  for (int off = 128; off > 0; off >>= 1) { if (t < off) red[t] = fminf(red[t], red[t + off]); __syncthreads(); }
  const float bmin = red[0];
  __syncthreads();
  red[t] = lmax; __syncthreads();
  for (int off = 128; off > 0; off >>= 1) { if (t < off) red[t] = fmaxf(red[t], red[t + off]); __syncthreads(); }
  if (t == 0) pmm[lid] = make_float2(bmin, red[0]);
}

// ---------------- final pass: pmm reduce (deterministic per block) + recompute + normalize + write ----------------
__global__ __launch_bounds__(256) void k_norm2(const float* __restrict__ x,
                                               const float* __restrict__ vm,
                                               const float* __restrict__ params,
                                               const float* __restrict__ Av,
                                               const float2* __restrict__ pmm,
                                               float* __restrict__ out) {
  const int t = threadIdx.x;
  __shared__ float rmn[256], rmx[256];
  float mn, sc;
  {
    float m0 = FINF, m1 = -FINF;
    for (int i = t; i < 1024; i += 256) {
      const float2 v = pmm[i];
      m0 = fminf(m0, v.x);
      m1 = fmaxf(m1, v.y);
    }
    rmn[t] = m0; rmx[t] = m1;
    __syncthreads();
    for (int off = 128; off > 0; off >>= 1) {
      if (t < off) {
        rmn[t] = fminf(rmn[t], rmn[t + off]);
        rmx[t] = fmaxf(rmx[t], rmx[t + off]);
      }
      __syncthreads();
    }
    mn = rmn[0];
    sc = 1.f / (rmx[0] - mn);
  }
  const int lid = blockIdx.x;                    // 4096
  const int swz = (lid & 7) * 512 + (lid >> 3);  // image b -> XCD (b>>1): vm is L2-local
  const int b = swz >> 8;
  const int y = (swz & 255) * 2 + (t >> 7);
  const int c0 = (t & 127) * 4;
  const float pb = params[b];
  const float a0 = Av[b * 3 + 0], a1 = Av[b * 3 + 1], a2 = Av[b * 3 + 2];
  const float4 v = *(const float4*)(vm + (size_t)b * 262144 + (size_t)y * 512 + c0);
  const float i0 = 1.f / fmaxf(1.f - pb * v.x, 0.01f);
  const float i1 = 1.f / fmaxf(1.f - pb * v.y, 0.01f);
  const float i2 = 1.f / fmaxf(1.f - pb * v.z, 0.01f);
  const float i3 = 1.f / fmaxf(1.f - pb * v.w, 0.01f);
  const size_t rowoff = (size_t)b * 3 * 262144 + (size_t)y * 512 + c0;
#pragma unroll
  for (int c = 0; c < 3; ++c) {
    const float a = (c == 0) ? a0 : ((c == 1) ? a1 : a2);
    const float4 xv = *(const float4*)(x + rowoff + (size_t)c * 262144);
    float4 o;
    o.x = (fmaf(xv.x - a, i0, a) - mn) * sc;
    o.y = (fmaf(xv.y - a, i1, a) - mn) * sc;
    o.z = (fmaf(xv.z - a, i2, a) - mn) * sc;
    o.w = (fmaf(xv.w - a, i3, a) - mn) * sc;
    *(float4*)(out + rowoff + (size_t)c * 262144) = o;
  }
}

extern "C" void kernel_launch(void* const* d_in, const int* in_sizes, int n_in,
                              void* d_out, int out_size, void* d_ws, size_t ws_size,
                              hipStream_t stream) {
  const float* x   = (const float*)d_in[0];
  const float* lat = (const float*)d_in[1];
  const float* w1  = (const float*)d_in[2];
  const float* b1  = (const float*)d_in[3];
  const float* w2  = (const float*)d_in[4];
  const float* b2  = (const float*)d_in[5];
  const float* w3  = (const float*)d_in[6];
  const float* b3  = (const float*)d_in[7];
  float* out = (float*)d_out;

  char* ws = (char*)d_ws;
  size_t off = 0;
  auto alloc = [&](size_t sz) -> void* {
    off = (off + 255) & ~(size_t)255;
    void* p = ws + off;
    off += sz;
    return p;
  };
  // One 16 MB region time-shared: h1part (conv) -> dc (hist/collect) -> vm (dchv/norm2).
  float*    big   = (float*)alloc((size_t)16 * 512 * 512 * sizeof(float));
  float*    h1p   = big;
  float*    dc    = big;
  float*    vmm   = big;
  float*    h1    = (float*)alloc(524288 * sizeof(float));
  unsigned short* wt2 = (unsigned short*)alloc(294912 * sizeof(unsigned short));
  float*    paramsp = (float*)alloc(16 * sizeof(float));
  float*    psum  = (float*)alloc(16 * 16 * sizeof(float));
  unsigned* hist  = (unsigned*)alloc(16 * 4096 * sizeof(unsigned));
  int*      cnt   = (int*)alloc(16 * sizeof(int));
  float*    bsums = (float*)alloc(16 * 32 * 3 * sizeof(float));
  float*    candv = (float*)alloc(16 * 4096 * sizeof(float));
  int*      candi = (int*)alloc(16 * 4096 * sizeof(int));
  float*    Av    = (float*)alloc(16 * 3 * sizeof(float));
  float2*   pmm   = (float2*)alloc(1024 * sizeof(float2));

  k_prep<<<1152, 256, 0, stream>>>(w1, wt2, hist, cnt);
  k_conv1m<<<dim3(16, 8, 2), 512, 0, stream>>>(lat, wt2, h1p);
  k_combine<<<512, 256, 0, stream>>>(h1p, h1, b1);   // must precede k_hist (big aliasing)
  k_hist<<<512, 256, 0, stream>>>(x, hist, dc);
  k_c2col<<<768, 256, 0, stream>>>(h1, w2, psum,
                                   x, dc, hist, cnt, candv, candi, bsums);
  k_finalA<<<16, 64, 0, stream>>>(x, bsums, cnt, hist, candv, candi,
                                  psum, b2, w3, b3, paramsp, Av);
  k_dchv<<<1024, 256, 0, stream>>>(x, Av, paramsp, vmm, pmm);
  k_norm2<<<4096, 256, 0, stream>>>(x, vmm, paramsp, Av, pmm, out);
}